// Round 9
// baseline (303.955 us; speedup 1.0000x reference)
//
#include <hip/hip_runtime.h>
#include <hip/hip_bf16.h>
#include <stdint.h>

// WanSelfAttention on gfx950, round 8b (type fix: __fp16 vectors for pkrtz/mfma).
// attn: QK operand-swapped => S^T in C-layout == PV's B-fragment layout
// (mfma_16x16x16_f16), so P never round-trips through LDS. V panels fp16
// with in-row key permutation so one b128 read = both K=16 A-frags.
// Fixed-shift softmax exp(s*scale-4); only the last global tile masked.

#define DIM  1536
#define NH   12
#define HD   128
#define LSEQ 2400
#define LPAD 2432
#define KT2  32
#define NT2  (LPAD / KT2)    // 76 global 32-key tiles
#define NTQ  19              // tiles per quarter

typedef __attribute__((ext_vector_type(8))) short short8;
typedef __attribute__((ext_vector_type(8))) __fp16 half8;
typedef __attribute__((ext_vector_type(4))) __fp16 half4;
typedef __attribute__((ext_vector_type(2))) __fp16 half2v;
typedef __attribute__((ext_vector_type(4))) float f32x4;
typedef unsigned short ushort_t;
typedef unsigned int   uint32;

__device__ __forceinline__ ushort_t f2bf(float f) {
  union { float f; unsigned u; } v; v.f = f;
  unsigned r = (v.u + 0x7fffu + ((v.u >> 16) & 1u)) >> 16;   // RNE
  return (ushort_t)r;
}
__device__ __forceinline__ float bf2f(ushort_t h) {
  union { unsigned u; float f; } v; v.u = ((unsigned)h) << 16;
  return v.f;
}
__device__ __forceinline__ void async16(void* lds, const void* g) {
  __builtin_amdgcn_global_load_lds(
      (const __attribute__((address_space(1))) uint32*)g,
      (__attribute__((address_space(3))) uint32*)lds, 16, 0, 0);
}
__device__ __forceinline__ uint4 pack8(const float* f) {
  uint4 u;
  u.x = (uint32)f2bf(f[0]) | ((uint32)f2bf(f[1]) << 16);
  u.y = (uint32)f2bf(f[2]) | ((uint32)f2bf(f[3]) << 16);
  u.z = (uint32)f2bf(f[4]) | ((uint32)f2bf(f[5]) << 16);
  u.w = (uint32)f2bf(f[6]) | ((uint32)f2bf(f[7]) << 16);
  return u;
}

// ---------------------------------------------------------------------------
// All f32->bf16 conversions in one launch. y=0: x (pad to LPAD, zeros);
// y=1..4: Wq/Wk/Wv/Wo.
// ---------------------------------------------------------------------------
__global__ void cvt_all(const float* __restrict__ x,
                        const float* __restrict__ W0, const float* __restrict__ W1,
                        const float* __restrict__ W2, const float* __restrict__ W3,
                        ushort_t* __restrict__ xd,
                        ushort_t* __restrict__ d0, ushort_t* __restrict__ d1,
                        ushort_t* __restrict__ d2, ushort_t* __restrict__ d3)
{
  const int z = blockIdx.y;
  const int i = blockIdx.x * 256 + threadIdx.x;
  if (z == 0) {
    uint4 u = {0, 0, 0, 0};
    if (i * 8 < LSEQ * DIM) {
      float f[8];
      *(float4*)f = *(const float4*)(x + i * 8);
      *(float4*)(f + 4) = *(const float4*)(x + i * 8 + 4);
      u = pack8(f);
    }
    *(uint4*)(xd + i * 8) = u;
    return;
  }
  if (blockIdx.x >= DIM * DIM / 2048) return;
  const float* s = (z == 1) ? W0 : ((z == 2) ? W1 : ((z == 3) ? W2 : W3));
  ushort_t* d    = (z == 1) ? d0 : ((z == 2) ? d1 : ((z == 3) ? d2 : d3));
  float f[8];
  *(float4*)f = *(const float4*)(s + i * 8);
  *(float4*)(f + 4) = *(const float4*)(s + i * 8 + 4);
  *(uint4*)(d + i * 8) = pack8(f);
}

// ---------------------------------------------------------------------------
// GEMM: C[m,n] = sum_k A[m,k]*B[n,k] + bias[n], async LDS staging (m97).
// ---------------------------------------------------------------------------
template<int OUT_F32>
__global__ __launch_bounds__(256) void gemm_bt(
    const ushort_t* __restrict__ Ap,
    const ushort_t* __restrict__ B0, const ushort_t* __restrict__ B1, const ushort_t* __restrict__ B2,
    const float* __restrict__ b0, const float* __restrict__ b1, const float* __restrict__ b2,
    void* __restrict__ D0, void* __restrict__ D1, void* __restrict__ D2,
    int Mout)
{
  const int z = blockIdx.y;
  const ushort_t* Bw  = (z == 0) ? B0 : ((z == 1) ? B1 : B2);
  const float* bias   = (z == 0) ? b0 : ((z == 1) ? b1 : b2);
  void* D             = (z == 0) ? D0 : ((z == 1) ? D1 : D2);

  const int bm = blockIdx.x / 12, bn = blockIdx.x % 12;
  const int tid = threadIdx.x;
  const int w = tid >> 6, lam = tid & 63;
  const int wr = w >> 1, wc = w & 1;
  const int lane15 = lam & 15, quad = lam >> 4;

  __shared__ __align__(16) char lds[32768];
  char* sA = lds;
  char* sB = lds + 16384;

  f32x4 acc[4][4];
#pragma unroll
  for (int i = 0; i < 4; ++i)
#pragma unroll
    for (int j = 0; j < 4; ++j) acc[i][j] = {};

  const int sm = (w * 32) + (lam >> 3);
  const int sc = (lam & 7);

  for (int k0 = 0; k0 < DIM; k0 += 64) {
    __syncthreads();
#pragma unroll
    for (int i = 0; i < 4; ++i) {
      const int li = w * 4096 + i * 1024;
      const int m = sm + i * 8;
      const int c = sc ^ (m & 7);
      async16(sA + li, Ap + (size_t)(bm * 128 + m) * DIM + k0 + c * 8);
      async16(sB + li, Bw + (size_t)(bn * 128 + m) * DIM + k0 + c * 8);
    }
    __syncthreads();
#pragma unroll
    for (int kc = 0; kc < 2; ++kc) {
      const int chunk = kc * 4 + quad;
      short8 af[4], bfr[4];
#pragma unroll
      for (int i = 0; i < 4; ++i) {
        const int m = wr * 64 + i * 16 + lane15;
        af[i] = *(const short8*)(sA + m * 128 + ((chunk ^ (m & 7)) * 16));
      }
#pragma unroll
      for (int j = 0; j < 4; ++j) {
        const int n = wc * 64 + j * 16 + lane15;
        bfr[j] = *(const short8*)(sB + n * 128 + ((chunk ^ (n & 7)) * 16));
      }
#pragma unroll
      for (int i = 0; i < 4; ++i)
#pragma unroll
        for (int j = 0; j < 4; ++j)
          acc[i][j] = __builtin_amdgcn_mfma_f32_16x16x32_bf16(af[i], bfr[j], acc[i][j], 0, 0, 0);
    }
  }

#pragma unroll
  for (int j = 0; j < 4; ++j) {
    const int n = bn * 128 + wc * 64 + j * 16 + lane15;
    const float bv = bias[n];
#pragma unroll
    for (int i = 0; i < 4; ++i) {
      const int mb = bm * 128 + wr * 64 + i * 16 + quad * 4;
#pragma unroll
      for (int r = 0; r < 4; ++r) {
        const int m = mb + r;
        const float val = acc[i][j][r] + bv;
        if (OUT_F32) {
          if (m < Mout) ((float*)D)[(size_t)m * DIM + n] = val;
        } else {
          ((ushort_t*)D)[(size_t)m * DIM + n] = f2bf(val);
        }
      }
    }
  }
}

// ---------------------------------------------------------------------------
// Fused: RMSNorm + 3D RoPE (head-major out)  AND  V -> fp16 32-key panels
// with in-row key permutation: key kk stored at
//   kk' = ((kk&15)>>2)*8 + (kk&3) + ((kk>>4)&1)*4
// so a 16B granule holds keys {g*4+0..3, 16+g*4+0..3} (two K=16 A-frags).
// ---------------------------------------------------------------------------
__global__ __launch_bounds__(256) void nr_vp(
    const ushort_t* __restrict__ qpre, const ushort_t* __restrict__ kpre,
    const ushort_t* __restrict__ vbf,
    const float* __restrict__ gq, const float* __restrict__ gk,
    const float* __restrict__ freqs,
    const int* __restrict__ seq_lens, const int* __restrict__ grid_sizes,
    ushort_t* __restrict__ qh, ushort_t* __restrict__ kh,
    ushort_t* __restrict__ vp)
{
  const int bx = blockIdx.x;
  const int tid = threadIdx.x;
  __shared__ float wsum[4];
  __shared__ float srstd;
  __shared__ ushort_t tbuf[32][33];

  if (bx >= 2 * LPAD) {
    const int vb = bx - 2 * LPAD;
    const int head = vb / (NT2 * 4);
    const int rem = vb - head * (NT2 * 4);
    const int t2 = rem >> 2;
    const int d0 = (rem & 3) * 32;
    const int l0 = t2 * 32;
    const int tx = tid & 31, ty = tid >> 5;
#pragma unroll
    for (int rr = 0; rr < 4; ++rr)
      tbuf[ty * 4 + rr][tx] = vbf[(size_t)(l0 + ty * 4 + rr) * DIM + head * HD + d0 + tx];
    __syncthreads();
    const int kk = ((tx & 15) >> 2) * 8 + (tx & 3) + ((tx >> 4) & 1) * 4;
#pragma unroll
    for (int rr = 0; rr < 4; ++rr) {
      const int d = d0 + ty * 4 + rr;
      union { __fp16 h; ushort_t u; } cv;
      cv.h = (__fp16)bf2f(tbuf[tx][ty * 4 + rr]);
      vp[(((size_t)head * NT2 + t2) * HD + d) * KT2 + kk] = cv.u;
    }
    return;
  }

  const int row = bx >> 1;
  const int which = bx & 1;
  const ushort_t* src = which ? kpre : qpre;
  const float* g = which ? gk : gq;
  ushort_t* dst = which ? kh : qh;

  float s = 0.f;
  if (tid < 192) {
    uint4 u = *(const uint4*)(src + (size_t)row * DIM + tid * 8);
    const uint32 uu[4] = {u.x, u.y, u.z, u.w};
#pragma unroll
    for (int i = 0; i < 4; ++i) {
      float a = bf2f((ushort_t)(uu[i] & 0xffff));
      float b = bf2f((ushort_t)(uu[i] >> 16));
      s += a * a + b * b;
    }
  }
#pragma unroll
  for (int off = 32; off; off >>= 1) s += __shfl_down(s, off, 64);
  if ((tid & 63) == 0) wsum[tid >> 6] = s;
  __syncthreads();
  if (tid == 0)
    srstd = rsqrtf((wsum[0] + wsum[1] + wsum[2] + wsum[3]) / (float)DIM + 1e-6f);
  __syncthreads();
  const float rstd = srstd;

  const int seq = seq_lens[0];
  const int h_ = grid_sizes[1], w_ = grid_sizes[2];
  const int hw = h_ * w_;
  const int fidx = row / hw;
  const int rem = row - fidx * hw;
  const int hidx = rem / w_;
  const int widx = rem - hidx * w_;
  const bool live = row < seq;

#pragma unroll
  for (int pp = 0; pp < 3; ++pp) {
    const int p = tid + pp * 256;
    const int c = p & 63, head = p >> 6;
    const int e_in = head * HD + 2 * c;
    uint32 xin = *(const uint32*)(src + (size_t)row * DIM + e_in);
    float x0 = bf2f((ushort_t)(xin & 0xffff));
    float x1 = bf2f((ushort_t)(xin >> 16));
    float2 gg = *(const float2*)(g + e_in);
    float y0 = x0 * rstd * gg.x, y1 = x1 * rstd * gg.y;
    const int pos = (c < 22) ? fidx : ((c < 43) ? hidx : widx);
    float4 R = *(const float4*)(freqs + ((size_t)pos * 64 + c) * 4);
    float o0 = R.x * y0 + R.y * y1;
    float o1 = R.z * y0 + R.w * y1;
    uint32 op = live ? ((uint32)f2bf(o0) | ((uint32)f2bf(o1) << 16)) : 0u;
    *(uint32*)(dst + ((size_t)head * LPAD + row) * HD + 2 * c) = op;
  }
}

// ---------------------------------------------------------------------------
// Flash attention, round 8: no P round-trip.
// S^T = mfma(kf, qf) (C-layout row=key, col=q) -> exp -> cvt_pkrtz -> directly
// the B-fragment of mfma_f32_16x16x16f16;  O^T = V^T . P^T accumulated in
// C-layout (row=d, col=q). Fixed shift 4; only global tile NT2-1 masked.
// ---------------------------------------------------------------------------
__global__ __launch_bounds__(256, 3) void attn8(
    const ushort_t* __restrict__ qh, const ushort_t* __restrict__ kh,
    const ushort_t* __restrict__ vp, const int* __restrict__ seq_lens,
    _Float16* __restrict__ op0, _Float16* __restrict__ op1,
    _Float16* __restrict__ op2, _Float16* __restrict__ op3,
    float* __restrict__ lp)
{
  const int qz = blockIdx.z;
  const int head = blockIdx.y;
  const int q0 = blockIdx.x * 128;
  const int tid = threadIdx.x;
  const int w = tid >> 6, lam = tid & 63;
  const int lane15 = lam & 15, quad = lam >> 4;
  const int seq = seq_lens[0];
  _Float16* op = (qz == 0) ? op0 : ((qz == 1) ? op1 : ((qz == 2) ? op2 : op3));

  __shared__ __align__(16) char kbuf[2][8192];      // [32 key][128 bf16]
  __shared__ __align__(16) char vbuf[2][8192];      // fp16, granule-swizzled

  // resident Q: wave w owns rows q0 + w*32 .. +31 (2 q-tiles)
  const ushort_t* qbase = qh + ((size_t)head * LPAD + q0 + w * 32) * HD;
  short8 qf[2][4];
#pragma unroll
  for (int qt = 0; qt < 2; ++qt)
#pragma unroll
    for (int kc = 0; kc < 4; ++kc)
      qf[qt][kc] = *(const short8*)(qbase + (qt * 16 + lane15) * HD + kc * 32 + quad * 8);

  f32x4 o[2][8];
#pragma unroll
  for (int qt = 0; qt < 2; ++qt)
#pragma unroll
    for (int dt = 0; dt < 8; ++dt) o[qt][dt] = {};
  float lacc[2] = {0.f, 0.f};

  const float C1 = 0.12752540f;    // (1/sqrt(128)) * log2(e)
  const float C2 = -5.7707802f;    // -4 * log2(e)

  const ushort_t* khh = kh + (size_t)head * LPAD * HD;
  const ushort_t* vph = vp + (size_t)head * NT2 * HD * KT2;

  const int krow0 = w * 8 + (lam >> 4);       // + i*4
  const int kslot = lam & 15;

#define STAGE(gt, b)                                                     \
  {                                                                      \
    const ushort_t* kg = khh + (size_t)(gt) * (KT2 * HD);                \
    const ushort_t* vg = vph + (size_t)(gt) * (HD * KT2);                \
    _Pragma("unroll")                                                    \
    for (int i = 0; i < 2; ++i) {                                        \
      const int li = w * 2048 + i * 1024;                                \
      const int kr = krow0 + i * 4;                                      \
      const int kc_ = kslot ^ (kr & 15);                                 \
      async16(kbuf[b] + li, kg + kr * HD + kc_ * 8);                     \
      const int G = w * 128 + i * 64 + lam;                              \
      const int l_ = (G >> 2) & 15;                                      \
      const int cc = (G & 3) ^ (l_ & 3);                                 \
      const int d_ = ((G >> 6) << 4) + l_;                               \
      async16(vbuf[b] + li, vg + d_ * KT2 + cc * 8);                     \
    }                                                                    \
  }

  const int tbase = qz * NTQ;
  STAGE(tbase, 0)
  __syncthreads();

  for (int t = 0; t < NTQ; ++t) {
    const int b = t & 1;
    const int gt = tbase + t;
    if (t + 1 < NTQ) STAGE(gt + 1, b ^ 1)

    // ---- QK^T, operand-swapped: S^T[key][q] ----
    f32x4 S[2][2];
    S[0][0] = {}; S[0][1] = {}; S[1][0] = {}; S[1][1] = {};
#pragma unroll
    for (int n0 = 0; n0 < 2; ++n0)
#pragma unroll
      for (int kc = 0; kc < 4; ++kc) {
        short8 kf = *(const short8*)(kbuf[b] + (n0 * 16 + lane15) * 256 +
                                     (((kc * 4 + quad) ^ lane15) * 16));
#pragma unroll
        for (int qt = 0; qt < 2; ++qt)
          S[qt][n0] = __builtin_amdgcn_mfma_f32_16x16x32_bf16(kf, qf[qt][kc], S[qt][n0], 0, 0, 0);
      }

    // ---- softmax: P^T = exp2(S*C1 + C2); values land as PV B-frags ----
    const bool tail = (gt == NT2 - 1);
    half4 pf[2][2];
#pragma unroll
    for (int qt = 0; qt < 2; ++qt)
#pragma unroll
      for (int n0 = 0; n0 < 2; ++n0) {
        float e[4];
#pragma unroll
        for (int r = 0; r < 4; ++r)
          e[r] = exp2f(fmaf(S[qt][n0][r], C1, C2));
        if (tail) {
#pragma unroll
          for (int r = 0; r < 4; ++r)
            if (gt * KT2 + n0 * 16 + quad * 4 + r >= seq) e[r] = 0.f;
        }
        lacc[qt] += (e[0] + e[1]) + (e[2] + e[3]);
        half2v lo = __builtin_amdgcn_cvt_pkrtz(e[0], e[1]);
        half2v hi = __builtin_amdgcn_cvt_pkrtz(e[2], e[3]);
        half4 pp = {lo[0], lo[1], hi[0], hi[1]};
        pf[qt][n0] = pp;
      }

    // ---- PV: O^T += V^T . P^T (K=16 f16 mfma, A-frag pairs from one b128) --
#pragma unroll
    for (int dt = 0; dt < 8; ++dt) {
      half8 vv = *(const half8*)(vbuf[b] + dt * 1024 +
                                 (lane15 * 4 + (quad ^ (lane15 & 3))) * 16);
      half4 vlo = {vv[0], vv[1], vv[2], vv[3]};
      half4 vhi = {vv[4], vv[5], vv[6], vv[7]};
#pragma unroll
      for (int qt = 0; qt < 2; ++qt) {
        o[qt][dt] = __builtin_amdgcn_mfma_f32_16x16x16f16(vlo, pf[qt][0], o[qt][dt], 0, 0, 0);
        o[qt][dt] = __builtin_amdgcn_mfma_f32_16x16x16f16(vhi, pf[qt][1], o[qt][dt], 0, 0, 0);
      }
    }
    __syncthreads();
  }
#undef STAGE

  // ---- epilogue: l reduce across quads; store fp16 partial O (row=q) ----
#pragma unroll
  for (int qt = 0; qt < 2; ++qt) {
    float l = lacc[qt];
    l += __shfl_xor(l, 16, 64);
    l += __shfl_xor(l, 32, 64);
    const float linv = 1.0f / l;
    const int qrow = q0 + w * 32 + qt * 16 + lane15;
    if (quad == 0)
      lp[((size_t)qz * NH + head) * LPAD + qrow] = l;
#pragma unroll
    for (int dt = 0; dt < 8; ++dt) {
      half2v a = __builtin_amdgcn_cvt_pkrtz(o[qt][dt][0] * linv, o[qt][dt][1] * linv);
      half2v c = __builtin_amdgcn_cvt_pkrtz(o[qt][dt][2] * linv, o[qt][dt][3] * linv);
      uint2 st;
      st.x = __builtin_bit_cast(uint32, a);
      st.y = __builtin_bit_cast(uint32, c);
      *(uint2*)(op + (size_t)qrow * DIM + head * HD + dt * 16 + quad * 4) = st;
    }
  }
}

// ---------------------------------------------------------------------------
// Merge 4 partials: out = sum(o_h * l_h) / sum(l_h) -> bf16.
// ---------------------------------------------------------------------------
__global__ void merge(const _Float16* __restrict__ o0, const _Float16* __restrict__ o1,
                      const _Float16* __restrict__ o2, const _Float16* __restrict__ o3,
                      const float* __restrict__ lp, ushort_t* __restrict__ attno)
{
  const int i = blockIdx.x * 256 + threadIdx.x;
  const int e = i * 8;
  const int m = e / DIM;
  const int head = (e - m * DIM) >> 7;
  float l[4];
#pragma unroll
  for (int h = 0; h < 4; ++h) l[h] = lp[((size_t)h * NH + head) * LPAD + m];
  const float inv = 1.0f / (l[0] + l[1] + l[2] + l[3]);
  half8 a = *(const half8*)(o0 + e);
  half8 b = *(const half8*)(o1 + e);
  half8 c = *(const half8*)(o2 + e);
  half8 d = *(const half8*)(o3 + e);
  const float w0 = l[0] * inv, w1 = l[1] * inv, w2 = l[2] * inv, w3 = l[3] * inv;
  float f[8];
#pragma unroll
  for (int j = 0; j < 8; ++j)
    f[j] = (float)a[j] * w0 + (float)b[j] * w1 + (float)c[j] * w2 + (float)d[j] * w3;
  *(uint4*)(attno + e) = pack8(f);
}

// ---------------------------------------------------------------------------
extern "C" void kernel_launch(void* const* d_in, const int* in_sizes, int n_in,
                              void* d_out, int out_size, void* d_ws, size_t ws_size,
                              hipStream_t stream)
{
  const float* x  = (const float*)d_in[0];
  const float* Wq = (const float*)d_in[1];
  const float* bq = (const float*)d_in[2];
  const float* Wk = (const float*)d_in[3];
  const float* bk = (const float*)d_in[4];
  const float* Wv = (const float*)d_in[5];
  const float* bv = (const float*)d_in[6];
  const float* Wo = (const float*)d_in[7];
  const float* bo = (const float*)d_in[8];
  const float* gq = (const float*)d_in[9];
  const float* gk = (const float*)d_in[10];
  const int* seq_lens   = (const int*)d_in[11];
  const int* grid_sizes = (const int*)d_in[12];
  const float* freqs    = (const float*)d_in[13];
  float* out = (float*)d_out;

  const size_t BUF = (size_t)LPAD * DIM * 2;       // 7,471,104 B
  const size_t WB  = (size_t)DIM * DIM * 2;        // 4,718,592 B
  char* ws = (char*)d_ws;
  dim3 blk(256);

  ushort_t* xbf  = (ushort_t*)(ws);                     // then vp, then attno
  ushort_t* wqb  = (ushort_t*)(ws + BUF);               // op3 after qkv gemm
  ushort_t* wkb  = (ushort_t*)(ws + BUF + WB);
  ushort_t* wvb  = (ushort_t*)(ws + BUF + 2 * WB);      // lp after qkv gemm
  ushort_t* wob  = (ushort_t*)(ws + BUF + 3 * WB);      // live until out gemm
  ushort_t* qpre = (ushort_t*)(ws + BUF + 4 * WB);      // op0 after nr_vp
  ushort_t* kpre = (ushort_t*)(ws + 2 * BUF + 4 * WB);  // op1 after nr_vp
  ushort_t* qh   = (ushort_t*)(ws + 3 * BUF + 4 * WB);
  ushort_t* kh   = (ushort_t*)(ws + 4 * BUF + 4 * WB);
  ushort_t* vbf  = (ushort_t*)(ws + 5 * BUF + 4 * WB);  // op2 after nr_vp
  ushort_t* vp    = xbf;                // xbf dead after qkv gemm
  ushort_t* attno = xbf;                // vp dead after attn
  _Float16* op0 = (_Float16*)qpre;
  _Float16* op1 = (_Float16*)kpre;
  _Float16* op2 = (_Float16*)vbf;
  _Float16* op3 = (_Float16*)wqb;       // wqb+wkb = 9.4 MB >= BUF
  float*    lp  = (float*)wvb;

  cvt_all<<<dim3(LPAD * DIM / 2048, 5), blk, 0, stream>>>(
      x, Wq, Wk, Wv, Wo, xbf, wqb, wkb, wvb, wob);
  gemm_bt<0><<<dim3(228, 3), blk, 0, stream>>>(
      xbf, wqb, wkb, wvb, bq, bk, bv, qpre, kpre, vbf, 0);
  nr_vp<<<dim3(2 * LPAD + NH * NT2 * 4), blk, 0, stream>>>(
      qpre, kpre, vbf, gq, gk, freqs, seq_lens, grid_sizes, qh, kh, vp);
  attn8<<<dim3(LPAD / 128, NH, 4), blk, 0, stream>>>(
      qh, kh, vp, seq_lens, op0, op1, op2, op3, lp);
  merge<<<dim3(LPAD * DIM / 2048), blk, 0, stream>>>(op0, op1, op2, op3, lp, attno);
  gemm_bt<1><<<dim3(228, 1), blk, 0, stream>>>(
      attno, wob, wob, wob, bo, bo, bo, out, out, out, LSEQ);
}